// Round 2
// baseline (62.561 us; speedup 1.0000x reference)
//
#include <hip/hip_runtime.h>
#include <math.h>

// IntraVolume_Attention, algebraically collapsed:
//   s_f = sum_g x_g e^{c x_f x_g} / sum_g e^{c x_f x_g},  c = dot(wq,wk)/sqrt(128)
//   out[row,d] = wv[d] * mean_f s_f
//
// R7: rank-1 logits -> s_f = MGF ratio at tau_f = c*x_f*xmax (u = x/xmax):
//   den_f = sum_n tau^n/n! M_n,  num_f = xmax * sum_n tau^n/n! M_{n+1},
//   M_n = sum_g u_g^n (n <= 64), guarded by tau<=26 && G<=3 with exact-exp
//   fallback. Landed 67.3 -> 62.2 us.
// R8: the series path was LDS-issue bound: Phase B read the power table
//   column-wise (1024 wave-level ds_read_b32) and Phase C re-read mom[]
//   per term (another 1024). Restructure:
//   - pow table transposed to [k][g]: waves reduce rows with dense
//     ds_read_b128 + in-wave shfl reduce; lane0 writes moments directly
//     (combine phase + barrier deleted).
//   - moments pre-packed per parity: mpack[p][j] = {M_{2j+p}, M_{2j+p+1}},
//     odd path pre-scaled by 1/(2j+1) so the p-ladder p *= r2 * c_j uses
//     parity-uniform literals. Phase C: 16 ds_read_b128/thread, parity on
//     lane&1, partner combine via one shfl_xor (LDS round-trip deleted).
//   - Phase A power ladder split across all 1024 threads (high half
//     starts at w^17 via squarings).
//   Barriers 7 -> 5; series LDS wave-instrs ~2100 -> ~650 (mostly b128).

#if __has_builtin(__builtin_amdgcn_exp2f)
#define EXP2(x) __builtin_amdgcn_exp2f(x)   // raw v_exp_f32
#else
#define EXP2(x) exp2f(x)
#endif

typedef float v2f __attribute__((ext_vector_type(2)));
typedef float v4f __attribute__((ext_vector_type(4)));

#define F_DIM 512

__global__ __launch_bounds__(1024) void intravol_attn(
    const float* __restrict__ x,    // [256, 512]
    const float* __restrict__ wq,   // [128]
    const float* __restrict__ wk,   // [128]
    const float* __restrict__ wv,   // [128]
    float* __restrict__ out)        // [256, 128]
{
    // pool union: series path = pow[33][512] (row0 = u, row k = w^k), 67.6 KB;
    // fallback path = pden[4][512] + pnum[4][512] (16 KB).
    __shared__ __align__(16) float pool[33 * F_DIM];
    __shared__ __align__(16) float xs[F_DIM];
    __shared__ __align__(16) float mpack[2][64];   // [par][2j+{0,1}]
    __shared__ float wmax[8], wmin[8], wsum[16];
    __shared__ float s_c, s_xmax, s_xmin, s_scale, s_inv;
    __shared__ int   s_fast;

    const int tid  = threadIdx.x;
    const int lane = tid & 63;
    const int wave = tid >> 6;
    const int row  = blockIdx.x;

    // ---- Phase 0: stage row, reduce max/min (waves 0..7), c (wave 8) ----
    float xv = 0.0f;
    if (tid < F_DIM) { xv = x[row * F_DIM + tid]; xs[tid] = xv; }
    if (wave < 8) {
        float mx = xv, mn = xv;
        for (int o = 32; o > 0; o >>= 1) {
            mx = fmaxf(mx, __shfl_down(mx, o));
            mn = fminf(mn, __shfl_down(mn, o));
        }
        if (lane == 0) { wmax[wave] = mx; wmin[wave] = mn; }
    } else if (wave == 8) {
        float d = wq[lane] * wk[lane] + wq[lane + 64] * wk[lane + 64];
        for (int o = 32; o > 0; o >>= 1) d += __shfl_down(d, o);
        if (lane == 0) s_c = d * 0.08838834764831845f;
    }
    __syncthreads();
    if (tid == 0) {
        float M = wmax[0], m_ = wmin[0];
        #pragma unroll
        for (int i = 1; i < 8; ++i) { M = fmaxf(M, wmax[i]); m_ = fminf(m_, wmin[i]); }
        s_xmax = M; s_xmin = m_;
        const float ap = fmaxf(M, 0.0f), an = fmaxf(-m_, 0.0f);
        const float xa = fmaxf(fmaxf(ap, an), 1e-30f);
        const float tm = fabsf(s_c) * xa * xa;             // max |tau|
        const float ms = fminf(ap, an) / xa;               // minority-side ratio
        s_scale = xa;
        s_inv   = 1.0f / xa;
        // G = tm*(1-ms): cancellation amplification exponent of the series.
        s_fast = (tm <= 26.0f) && (tm * (1.0f - ms) <= 3.0f) ? 1 : 0;
        mpack[0][0] = (float)F_DIM;                        // M_0
    }
    __syncthreads();

    float sf = 0.0f;

    if (s_fast) {
        // ---- Phase A: transposed power table pow[k][g] ----
        // thread g (<512): row0 = u, rows 1..16 = w^1..w^16 (serial ladder);
        // thread g+512: rows 17..32 = w^17..w^32 (start via squarings).
        {
            const int g = tid & 511;
            if (tid < F_DIM) {
                const float u = xv * s_inv;
                const float w = u * u;
                pool[g] = u;
                float p = w;
                #pragma unroll
                for (int k = 1; k <= 16; ++k) { pool[k * F_DIM + g] = p; p *= w; }
            } else {
                const float u  = xs[g] * s_inv;
                const float w  = u * u;
                const float w2 = w * w, w4 = w2 * w2, w8 = w4 * w4;
                float p = w8 * w8 * w;      // w^17
                #pragma unroll
                for (int k = 17; k <= 32; ++k) { pool[k * F_DIM + g] = p; p *= w; }
            }
        }
        __syncthreads();

        // ---- Phase B: wave w reduces rows {w, w+16} (+32 for wave 0).
        // Row k>=1: plain sum -> M_2k, fma with u -> M_{2k+1}.
        // Row 0 (u): plain sum -> M_1. Lane 0 scatters into mpack with the
        // odd-path 1/(2j+1) folding.
        {
            const v4f* ubp = (const v4f*)pool;
            const v4f ua = ubp[lane];          // u[4*lane .. +3]
            const v4f uc = ubp[64 + lane];     // u[256+4*lane .. +3]

            auto do_row = [&](int k) {
                const v4f* rb = (const v4f*)&pool[k * F_DIM];
                const v4f pa = rb[lane];
                const v4f pb = rb[64 + lane];
                float sA = ((pa.x + pa.y) + (pa.z + pa.w)) +
                           ((pb.x + pb.y) + (pb.z + pb.w));
                float sB = fmaf(ua.x, pa.x, fmaf(ua.y, pa.y,
                           fmaf(ua.z, pa.z, fmaf(ua.w, pa.w,
                           fmaf(uc.x, pb.x, fmaf(uc.y, pb.y,
                           fmaf(uc.z, pb.z, uc.w * pb.w)))))));
                #pragma unroll
                for (int o = 32; o > 0; o >>= 1) {
                    sA += __shfl_down(sA, o);
                    sB += __shfl_down(sB, o);
                }
                if (lane == 0) {
                    if (k == 0) {
                        mpack[0][1] = sA;                          // M_1
                        mpack[1][0] = sA;                          // M_1 / 1
                    } else {
                        if (k < 32) {
                            mpack[0][2 * k]     = sA;              // M_2k
                            mpack[0][2 * k + 1] = sB;              // M_2k+1
                            mpack[1][2 * k]     = sB / (float)(2 * k + 1);
                        }
                        mpack[1][2 * k - 1]     = sA / (float)(2 * k - 1);
                    }
                }
            };
            do_row(wave);
            do_row(wave + 16);
            if (wave == 0) do_row(32);
        }
        __syncthreads();

        // ---- Phase C: series eval. f = wave*32 + lane/2, par = lane&1.
        // p_j = tau^{2j+par} / (2j)!  (odd-path 1/(2j+1) folded in mpack).
        {
            const int par = lane & 1;
            const int f   = (wave << 5) | (lane >> 1);
            const float tau = s_c * xs[f] * s_scale;
            const float r2  = tau * tau;
            float p   = par ? tau : 1.0f;
            float den = 0.0f, num = 0.0f;
            const v4f* mp = (const v4f*)&mpack[par][0];
            #pragma unroll
            for (int t = 0; t < 16; ++t) {
                const v4f m = mp[t];           // {j=2t, j=2t+1} pairs
                den = fmaf(m.x, p, den);
                num = fmaf(m.y, p, num);
                p *= r2;
                p *= (1.0f / (float)((4 * t + 1) * (4 * t + 2)));
                den = fmaf(m.z, p, den);
                num = fmaf(m.w, p, num);
                p *= r2;
                p *= (1.0f / (float)((4 * t + 3) * (4 * t + 4)));
            }
            den += __shfl_xor(den, 1);         // combine parities in-pair
            num += __shfl_xor(num, 1);
            sf = s_scale * num / den;          // each f held by 2 lanes
        }
    } else {
        // ---- Fallback: exact exp path (R6 kernel, verbatim) ----
        float (*pden)[F_DIM] = (float (*)[F_DIM])pool;
        float (*pnum)[F_DIM] = (float (*)[F_DIM])(pool + 4 * F_DIM);

        const float LOG2E = 1.4426950408889634f;
        const int f0 = (tid & 255) << 1;    // even f
        const int sl = tid >> 8;            // g-slice 0..3

        const float a0 = s_c * xs[f0]     * LOG2E;
        const float a1 = s_c * xs[f0 + 1] * LOG2E;
        v2f a2  = { a0, a1 };
        v2f bb  = { -((a0 >= 0.0f) ? a0 * s_xmax : a0 * s_xmin),
                    -((a1 >= 0.0f) ? a1 * s_xmax : a1 * s_xmin) };
        v2f den = { 0.0f, 0.0f };
        v2f num = { 0.0f, 0.0f };

        const float4* xs4 = (const float4*)&xs[sl << 7];
        #pragma unroll 8
        for (int i = 0; i < 32; ++i) {      // 32 broadcast ds_read_b128 = 128 g
            const float4 v = xs4[i];
            const float xg_[4] = { v.x, v.y, v.z, v.w };
            #pragma unroll
            for (int j = 0; j < 4; ++j) {
                const float xg = xg_[j];
                const v2f xg2 = { xg, xg };
                const v2f arg = __builtin_elementwise_fma(a2, xg2, bb);
                const v2f e   = { EXP2(arg.x), EXP2(arg.y) };
                den += e;
                num = __builtin_elementwise_fma(e, xg2, num);
            }
        }
        *(v2f*)&pden[sl][f0] = den;
        *(v2f*)&pnum[sl][f0] = num;
        __syncthreads();

        if (tid < F_DIM) {
            float D = 0.0f, N = 0.0f;
            #pragma unroll
            for (int s = 0; s < 4; ++s) { D += pden[s][tid]; N += pnum[s][tid]; }
            sf = N / D;
        }
    }

    // ---- Common epilogue: mean over f, scale by wv ----
    // Fast path: every f appears on 2 lanes -> divide by 1024; fallback: 512.
    float t = sf;
    for (int o = 32; o > 0; o >>= 1) t += __shfl_down(t, o);
    if (lane == 0) wsum[wave] = t;
    __syncthreads();

    if (tid < 128) {
        const float esc = s_fast ? (1.0f / 1024.0f) : (1.0f / 512.0f);
        float total = 0.0f;
        #pragma unroll
        for (int i = 0; i < 16; ++i) total += wsum[i];
        out[row * 128 + tid] = total * esc * wv[tid];
    }
}

extern "C" void kernel_launch(void* const* d_in, const int* in_sizes, int n_in,
                              void* d_out, int out_size, void* d_ws, size_t ws_size,
                              hipStream_t stream) {
    const float* x  = (const float*)d_in[0];  // [8,32,512]
    const float* wq = (const float*)d_in[1];  // [1,128]
    const float* wk = (const float*)d_in[2];  // [1,128]
    const float* wv = (const float*)d_in[3];  // [1,128]
    float* out = (float*)d_out;               // [8,32,128]

    intravol_attn<<<256, 1024, 0, stream>>>(x, wq, wk, wv, out);
}